// Round 1
// baseline (59.228 us; speedup 1.0000x reference)
//
#include <hip/hip_runtime.h>
#include <math.h>

#define LL 2048
#define LSHIFT 11
#define LMASK 2047
#define NTOT (LL * LL)

// ---------- helpers ----------

// c_profit / d_profit, replicating per-op f32 rounding:
//   d_profit = (coop / 5.0f) * 3.8f        (div and mul each round-to-nearest)
//   c_profit = d_profit_preround... NO: c_profit = ((coop/5)*3.8) - 1, each op rounded.
__device__ __forceinline__ float dprof(int coop) {
    return __fmul_rn(__fdiv_rn((float)coop, 5.0f), 3.8f);
}

// greedy action + q_new chain, exact per-op f32 to match reference
__device__ __forceinline__ void qstep(int A, float4 q, float2 tr, float profit,
                                      float& qn, int& Bact) {
    float qa0 = A ? q.z : q.x;
    float qa1 = A ? q.w : q.y;
    float mx = fmaxf(qa0, qa1);
    // masked = is_max - (1-is_max)*1e9 -> exactly 1.0f or -1e9f; then + tie
    float v0 = __fadd_rn(qa0 == mx ? 1.0f : -1.0e9f, tr.x);
    float v1 = __fadd_rn(qa1 == mx ? 1.0f : -1.0e9f, tr.y);
    Bact = (v1 > v0) ? 1 : 0;   // argmax, first occurrence on ties
    // EPSILON = -1.0, eps_rand in [0,1) -> eps_mask always true -> B = greedy
    float qb0 = Bact ? q.z : q.x;
    float qb1 = Bact ? q.w : q.y;
    float mn = fmaxf(qb0, qb1);                 // max_a' Q_old[n, B, a']
    float qold = A ? (Bact ? q.w : q.z) : (Bact ? q.y : q.x);
    // q_new = q_old + 0.8*(profit + 0.8*max_next - q_old), per-op rounded
    float a1 = __fmul_rn(0.8f, mn);
    float a2 = __fadd_rn(profit, a1);
    float a3 = __fsub_rn(a2, qold);
    float a4 = __fmul_rn(0.8f, a3);
    qn = __fadd_rn(qold, a4);
}

// ---------- kernel 1: payoff stencil + greedy + Q update ----------

__global__ __launch_bounds__(256) void k_payoff_q(
    const int* __restrict__ type, const float* __restrict__ Q,
    const float* __restrict__ tie, float* __restrict__ outQ,
    float* __restrict__ outP, float* __restrict__ p2w,
    unsigned char* __restrict__ Bw, int use_ws)
{
    int n = blockIdx.x * 256 + threadIdx.x;
    int i = n >> LSHIFT, j = n & LMASK;
    int im = (i - 1) & LMASK, ip = (i + 1) & LMASK;
    int im2 = (i - 2) & LMASK, ip2 = (i + 2) & LMASK;
    int jm = (j - 1) & LMASK, jp = (j + 1) & LMASK;
    int jm2 = (j - 2) & LMASK, jp2 = (j + 2) & LMASK;
#define TY(r, c) type[((r) << LSHIFT) | (c)]
    int t00 = TY(i, j);
    int tN = TY(im, j), tS = TY(ip, j), tW = TY(i, jm), tE = TY(i, jp);
    int tNN = TY(im2, j), tSS = TY(ip2, j), tWW = TY(i, jm2), tEE = TY(i, jp2);
    int tNW = TY(im, jm), tNE = TY(im, jp), tSW = TY(ip, jm), tSE = TY(ip, jp);
#undef TY
    // coop_num (integer, exact) for center + 4 plus-neighbors
    int coopC = t00 + tN + tS + tW + tE;
    int coopN = tN + tNN + t00 + tNW + tNE;
    int coopS = tS + t00 + tSS + tSW + tSE;
    int coopW = tW + tNW + tSW + tWW + t00;
    int coopE = tE + tNE + tSE + t00 + tEE;

    float dC = dprof(coopC), dN = dprof(coopN), dS = dprof(coopS),
          dW = dprof(coopW), dE = dprof(coopE);
    float cC = __fsub_rn(dC, 1.0f), cN = __fsub_rn(dN, 1.0f),
          cS = __fsub_rn(dS, 1.0f), cW = __fsub_rn(dW, 1.0f),
          cE = __fsub_rn(dE, 1.0f);
    // _neighbor5 order: center + up + down + left + right, left-assoc adds
    float c5 = __fadd_rn(__fadd_rn(__fadd_rn(__fadd_rn(cC, cN), cS), cW), cE);
    float d5 = __fadd_rn(__fadd_rn(__fadd_rn(__fadd_rn(dC, dN), dS), dW), dE);
    float profit = t00 ? c5 : d5;   // c5*c + d5*d with c,d in {0,1} is exact select

    float4 q = ((const float4*)Q)[n];
    float2 tr = ((const float2*)tie)[n];
    float qn; int Bact;
    qstep(t00, q, tr, profit, qn, Bact);

    float4 qo = q;
    if (t00 == 0) { if (Bact == 0) qo.x = qn; else qo.y = qn; }
    else          { if (Bact == 0) qo.z = qn; else qo.w = qn; }
    ((float4*)outQ)[n] = qo;
    outP[n] = profit;
    if (use_ws) { p2w[n] = qn; Bw[n] = (unsigned char)Bact; }
}

// ---------- kernel 2 (ws path): fermi imitation ----------

__device__ __forceinline__ int neigh_idx(int n, int d) {
    int i = n >> LSHIFT, j = n & LMASK;
    // rolls: 0:(+1,ax1)->(i,j-1) left; 1:(-1,ax1)->(i,j+1) right;
    //        2:(+1,ax0)->(i-1,j) up;   3:(-1,ax0)->(i+1,j) down
    int ni = i, nj = j;
    if (d == 0)      nj = (j - 1) & LMASK;
    else if (d == 1) nj = (j + 1) & LMASK;
    else if (d == 2) ni = (i - 1) & LMASK;
    else             ni = (i + 1) & LMASK;
    return (ni << LSHIFT) | nj;
}

__global__ __launch_bounds__(256) void k_fermi_ws(
    const int* __restrict__ type, const int* __restrict__ dir,
    const float* __restrict__ lp, const float* __restrict__ p2w,
    const unsigned char* __restrict__ Bw, float* __restrict__ outT)
{
    int n = blockIdx.x * 256 + threadIdx.x;
    int nn = neigh_idx(n, dir[n]);
    double pc = (double)p2w[n];
    double pn = (double)p2w[nn];
    // W = sigmoid((pn-pc)/0.5) = 1/(1+exp(2*(pc-pn))), in double (near-true value)
    double W = 1.0 / (1.0 + exp((pc - pn) * 2.0));
    float l = lp[n];
    int tsel = ((double)l <= W) ? (int)Bw[nn] : type[n];
    outT[n] = (float)tsel;
}

// ---------- kernel 2 (stateless fallback): recompute q_new/B per cell ----------

__global__ __launch_bounds__(256) void k_fermi_rc(
    const int* __restrict__ type, const int* __restrict__ dir,
    const float* __restrict__ lp, const float* __restrict__ Q,
    const float* __restrict__ tie, const float* __restrict__ outP,
    float* __restrict__ outT)
{
    int n = blockIdx.x * 256 + threadIdx.x;
    int nn = neigh_idx(n, dir[n]);
    float qnc, qnn; int Bc, Bn;
    {
        int A = type[n];
        float4 q = ((const float4*)Q)[n];
        float2 tr = ((const float2*)tie)[n];
        qstep(A, q, tr, outP[n], qnc, Bc);
    }
    {
        int A = type[nn];
        float4 q = ((const float4*)Q)[nn];
        float2 tr = ((const float2*)tie)[nn];
        qstep(A, q, tr, outP[nn], qnn, Bn);
    }
    double W = 1.0 / (1.0 + exp(((double)qnc - (double)qnn) * 2.0));
    float l = lp[n];
    int tsel = ((double)l <= W) ? Bn : type[n];
    outT[n] = (float)tsel;
}

// ---------- host ----------

extern "C" void kernel_launch(void* const* d_in, const int* in_sizes, int n_in,
                              void* d_out, int out_size, void* d_ws, size_t ws_size,
                              hipStream_t stream) {
    const int*   type = (const int*)d_in[0];
    const float* Q    = (const float*)d_in[1];
    const float* tie  = (const float*)d_in[2];
    // d_in[3] random_type and d_in[4] eps_rand are dead: eps_rand >= -1 always
    const int*   dir  = (const int*)d_in[5];
    const float* lp   = (const float*)d_in[6];

    float* out  = (float*)d_out;
    float* outT = out;                       // [N]  type_t2
    float* outQ = out + (size_t)NTOT;        // [4N] Q_new
    float* outP = out + (size_t)NTOT * 5;    // [N]  profit

    size_t need = (size_t)NTOT * 5;          // p2 (4N bytes) + B (N bytes)
    int use_ws = (ws_size >= need) ? 1 : 0;
    float* p2w = (float*)d_ws;
    unsigned char* Bw = (unsigned char*)d_ws + (size_t)NTOT * 4;

    dim3 blk(256), grd(NTOT / 256);
    hipLaunchKernelGGL(k_payoff_q, grd, blk, 0, stream,
                       type, Q, tie, outQ, outP,
                       use_ws ? p2w : nullptr, use_ws ? Bw : nullptr, use_ws);
    if (use_ws) {
        hipLaunchKernelGGL(k_fermi_ws, grd, blk, 0, stream,
                           type, dir, lp, p2w, Bw, outT);
    } else {
        hipLaunchKernelGGL(k_fermi_rc, grd, blk, 0, stream,
                           type, dir, lp, Q, tie, outP, outT);
    }
}